// Round 2
// baseline (278.696 us; speedup 1.0000x reference)
//
#include <hip/hip_runtime.h>

#define SIGMA 0.5f
#define BB 32
#define NVV 6890
#define NFF 13776
#define MAXC 8
#define NCC (NFF * MAXC)

// per-(batch,face) record: c[3], n[3], v0[3], v1[3], v2[3], pad -> 16 floats = 64B
#define REC_FLOATS 16
#define REC_BYTES  ((size_t)BB * NFF * REC_FLOATS * sizeof(float))

__device__ __forceinline__ float3 loadv3(const float* __restrict__ p) {
    return make_float3(p[0], p[1], p[2]);
}

// one side of the symmetric penetration: query verts q0..q2 in the cone field
// defined by centroid c and unit normal n
__device__ __forceinline__ float penSide(float cx, float cy, float cz,
                                         float nx, float ny, float nz,
                                         const float3* q) {
    float pen = 0.0f;
#pragma unroll
    for (int v = 0; v < 3; ++v) {
        float dx = q[v].x - cx;
        float dy = q[v].y - cy;
        float dz = q[v].z - cz;
        float h = dx * nx + dy * ny + dz * nz;
        float r = sqrtf(dx * dx + dy * dy + dz * dz);
        float phi = fmaxf(SIGMA - r, 0.0f);
        pen += (h < 0.0f) ? phi * h * h : 0.0f;
    }
    return pen;
}

// ---------------- phase 1: per-(b,f) face records ----------------
__global__ __launch_bounds__(256) void face_kernel(
    const float* __restrict__ vertices,   // [B, NV, 3]
    const int*   __restrict__ faces,      // [NF, 3]
    float*       __restrict__ rec,        // [B*NF, 16]
    float*       __restrict__ accum)
{
    const int i = blockIdx.x * blockDim.x + threadIdx.x;
    if (i == 0) accum[0] = 0.0f;          // zero the reduction slot (same stream, pre-pair)
    if (i >= BB * NFF) return;
    const int b = i / NFF;
    const int f = i - b * NFF;

    const float* vb = vertices + (size_t)b * (NVV * 3);
    const int i0 = faces[f * 3 + 0];
    const int i1 = faces[f * 3 + 1];
    const int i2 = faces[f * 3 + 2];
    float3 v0 = loadv3(vb + (size_t)i0 * 3);
    float3 v1 = loadv3(vb + (size_t)i1 * 3);
    float3 v2 = loadv3(vb + (size_t)i2 * 3);

    const float third = 1.0f / 3.0f;
    float cx = (v0.x + v1.x + v2.x) * third;
    float cy = (v0.y + v1.y + v2.y) * third;
    float cz = (v0.z + v1.z + v2.z) * third;

    float e1x = v1.x - v0.x, e1y = v1.y - v0.y, e1z = v1.z - v0.z;
    float e2x = v2.x - v0.x, e2y = v2.y - v0.y, e2z = v2.z - v0.z;
    float nx = e1y * e2z - e1z * e2y;
    float ny = e1z * e2x - e1x * e2z;
    float nz = e1x * e2y - e1y * e2x;
    float inv = 1.0f / (sqrtf(nx * nx + ny * ny + nz * nz) + 1e-8f);
    nx *= inv; ny *= inv; nz *= inv;

    float4* r = (float4*)(rec + (size_t)i * REC_FLOATS);
    r[0] = make_float4(cx, cy, cz, nx);
    r[1] = make_float4(ny, nz, v0.x, v0.y);
    r[2] = make_float4(v0.z, v1.x, v1.y, v1.z);
    r[3] = make_float4(v2.x, v2.y, v2.z, 0.0f);
}

// ---------------- phase 2: per-pair combine ----------------
__global__ __launch_bounds__(256) void pair_kernel(
    const float* __restrict__ rec,        // [B*NF, 16]
    const int2*  __restrict__ cidx,       // [B, NC]
    float*       __restrict__ accum)
{
    const int i = blockIdx.x * blockDim.x + threadIdx.x;
    float pen = 0.0f;

    if (i < BB * NCC) {
        const int b = i / NCC;
        const int2 pr = cidx[i];
        if (pr.x >= 0) {
            const int f0 = pr.x;
            const int f1 = pr.y < 0 ? 0 : pr.y;
            const float4* ra = (const float4*)(rec + ((size_t)b * NFF + f0) * REC_FLOATS);
            const float4* rb = (const float4*)(rec + ((size_t)b * NFF + f1) * REC_FLOATS);
            float4 a0 = ra[0], a1 = ra[1], a2 = ra[2], a3 = ra[3];
            float4 b0 = rb[0], b1 = rb[1], b2 = rb[2], b3 = rb[3];

            float3 qa[3] = { make_float3(a1.z, a1.w, a2.x),
                             make_float3(a2.y, a2.z, a2.w),
                             make_float3(a3.x, a3.y, a3.z) };
            float3 qb[3] = { make_float3(b1.z, b1.w, b2.x),
                             make_float3(b2.y, b2.z, b2.w),
                             make_float3(b3.x, b3.y, b3.z) };

            // intruder verts in receiver field + receiver verts in intruder field
            pen = penSide(a0.x, a0.y, a0.z, a0.w, a1.x, a1.y, qb)
                + penSide(b0.x, b0.y, b0.z, b0.w, b1.x, b1.y, qa);
        }
    }

#pragma unroll
    for (int off = 32; off > 0; off >>= 1)
        pen += __shfl_down(pen, off, 64);

    __shared__ float smem[4];
    const int lane = threadIdx.x & 63;
    const int wv   = threadIdx.x >> 6;
    if (lane == 0) smem[wv] = pen;
    __syncthreads();
    if (threadIdx.x == 0)
        atomicAdd(accum, smem[0] + smem[1] + smem[2] + smem[3]);
}

// ---------------- fallback: direct per-pair (no workspace) ----------------
__global__ void init_kernel(float* __restrict__ accum) { accum[0] = 0.0f; }

__device__ __forceinline__ float conePen(float3 a0, float3 a1, float3 a2,
                                         float3 q0, float3 q1, float3 q2) {
    const float third = 1.0f / 3.0f;
    float cx = (a0.x + a1.x + a2.x) * third;
    float cy = (a0.y + a1.y + a2.y) * third;
    float cz = (a0.z + a1.z + a2.z) * third;
    float e1x = a1.x - a0.x, e1y = a1.y - a0.y, e1z = a1.z - a0.z;
    float e2x = a2.x - a0.x, e2y = a2.y - a0.y, e2z = a2.z - a0.z;
    float nx = e1y * e2z - e1z * e2y;
    float ny = e1z * e2x - e1x * e2z;
    float nz = e1x * e2y - e1y * e2x;
    float inv = 1.0f / (sqrtf(nx * nx + ny * ny + nz * nz) + 1e-8f);
    nx *= inv; ny *= inv; nz *= inv;
    float3 q[3] = {q0, q1, q2};
    float pen = 0.0f;
#pragma unroll
    for (int v = 0; v < 3; ++v) {
        float dx = q[v].x - cx, dy = q[v].y - cy, dz = q[v].z - cz;
        float h = dx * nx + dy * ny + dz * nz;
        float r = sqrtf(dx * dx + dy * dy + dz * dz);
        float phi = fmaxf(SIGMA - r, 0.0f);
        pen += (h < 0.0f) ? phi * h * h : 0.0f;
    }
    return pen;
}

__global__ __launch_bounds__(256) void pen_direct(
    const float* __restrict__ vertices, const int* __restrict__ faces,
    const int2* __restrict__ cidx, float* __restrict__ accum)
{
    const int i = blockIdx.x * blockDim.x + threadIdx.x;
    float pen = 0.0f;
    if (i < BB * NCC) {
        const int b = i / NCC;
        const int2 pr = cidx[i];
        if (pr.x >= 0) {
            const int f0 = pr.x;
            const int f1 = pr.y < 0 ? 0 : pr.y;
            const float* vb = vertices + (size_t)b * (NVV * 3);
            float3 a0 = loadv3(vb + (size_t)faces[f0*3+0] * 3);
            float3 a1 = loadv3(vb + (size_t)faces[f0*3+1] * 3);
            float3 a2 = loadv3(vb + (size_t)faces[f0*3+2] * 3);
            float3 b0 = loadv3(vb + (size_t)faces[f1*3+0] * 3);
            float3 b1 = loadv3(vb + (size_t)faces[f1*3+1] * 3);
            float3 b2 = loadv3(vb + (size_t)faces[f1*3+2] * 3);
            pen = conePen(a0,a1,a2,b0,b1,b2) + conePen(b0,b1,b2,a0,a1,a2);
        }
    }
#pragma unroll
    for (int off = 32; off > 0; off >>= 1)
        pen += __shfl_down(pen, off, 64);
    __shared__ float smem[4];
    const int lane = threadIdx.x & 63;
    const int wv   = threadIdx.x >> 6;
    if (lane == 0) smem[wv] = pen;
    __syncthreads();
    if (threadIdx.x == 0)
        atomicAdd(accum, smem[0] + smem[1] + smem[2] + smem[3]);
}

__global__ void fin_kernel(const float* __restrict__ accum,
                           const float* __restrict__ weight,
                           float* __restrict__ out)
{
    out[0] = accum[0] * weight[0] * (1.0f / (float)BB);
}

extern "C" void kernel_launch(void* const* d_in, const int* in_sizes, int n_in,
                              void* d_out, int out_size, void* d_ws, size_t ws_size,
                              hipStream_t stream) {
    const float* vertices = (const float*)d_in[4];
    const float* weight   = (const float*)d_in[5];
    const int*   faces    = (const int*)d_in[6];
    const int2*  cidx     = (const int2*)d_in[7];
    float* out = (float*)d_out;

    const int totalPairs = BB * NCC;                 // 3,526,656
    const int pairBlocks = (totalPairs + 255) / 256; // 13,776

    if (ws_size >= REC_BYTES + 256) {
        float* rec   = (float*)d_ws;
        float* accum = (float*)((char*)d_ws + REC_BYTES);

        const int totalFaces = BB * NFF;             // 440,832
        face_kernel<<<dim3((totalFaces + 255) / 256), dim3(256), 0, stream>>>(
            vertices, faces, rec, accum);
        pair_kernel<<<dim3(pairBlocks), dim3(256), 0, stream>>>(rec, cidx, accum);
        fin_kernel<<<dim3(1), dim3(1), 0, stream>>>(accum, weight, out);
    } else {
        float* accum = (float*)d_ws;
        init_kernel<<<dim3(1), dim3(1), 0, stream>>>(accum);
        pen_direct<<<dim3(pairBlocks), dim3(256), 0, stream>>>(vertices, faces, cidx, accum);
        fin_kernel<<<dim3(1), dim3(1), 0, stream>>>(accum, weight, out);
    }
}

// Round 3
// 150.421 us; speedup vs baseline: 1.8528x; 1.8528x over previous
//
#include <hip/hip_runtime.h>

#define SIGMA 0.5f
#define BB 32
#define NVV 6890
#define NFF 13776
#define MAXC 8
#define NCC (NFF * MAXC)

// per-(batch,face) record: c[3], n[3], v0[3], v1[3], v2[3], pad -> 16 floats = 64B
#define REC_FLOATS 16
#define REC_BYTES  ((size_t)BB * NFF * REC_FLOATS * sizeof(float))

// pair grid: x = batch (32), y = slot (431) -> batch b pinned to XCD b%8
#define SLOTS ((NCC + 255) / 256)        // 431
#define NPART (BB * SLOTS)               // 13792 per-block partials

__device__ __forceinline__ float3 loadv3(const float* __restrict__ p) {
    return make_float3(p[0], p[1], p[2]);
}

__device__ __forceinline__ float penSide(float cx, float cy, float cz,
                                         float nx, float ny, float nz,
                                         const float3* q) {
    float pen = 0.0f;
#pragma unroll
    for (int v = 0; v < 3; ++v) {
        float dx = q[v].x - cx;
        float dy = q[v].y - cy;
        float dz = q[v].z - cz;
        float h = dx * nx + dy * ny + dz * nz;
        float r = sqrtf(dx * dx + dy * dy + dz * dz);
        float phi = fmaxf(SIGMA - r, 0.0f);
        pen += (h < 0.0f) ? phi * h * h : 0.0f;
    }
    return pen;
}

// ---------------- phase 1: per-(b,f) face records ----------------
__global__ __launch_bounds__(256) void face_kernel(
    const float* __restrict__ vertices,   // [B, NV, 3]
    const int*   __restrict__ faces,      // [NF, 3]
    float*       __restrict__ rec)        // [B*NF, 16]
{
    const int i = blockIdx.x * blockDim.x + threadIdx.x;
    if (i >= BB * NFF) return;
    const int b = i / NFF;
    const int f = i - b * NFF;

    const float* vb = vertices + (size_t)b * (NVV * 3);
    const int i0 = faces[f * 3 + 0];
    const int i1 = faces[f * 3 + 1];
    const int i2 = faces[f * 3 + 2];
    float3 v0 = loadv3(vb + (size_t)i0 * 3);
    float3 v1 = loadv3(vb + (size_t)i1 * 3);
    float3 v2 = loadv3(vb + (size_t)i2 * 3);

    const float third = 1.0f / 3.0f;
    float cx = (v0.x + v1.x + v2.x) * third;
    float cy = (v0.y + v1.y + v2.y) * third;
    float cz = (v0.z + v1.z + v2.z) * third;

    float e1x = v1.x - v0.x, e1y = v1.y - v0.y, e1z = v1.z - v0.z;
    float e2x = v2.x - v0.x, e2y = v2.y - v0.y, e2z = v2.z - v0.z;
    float nx = e1y * e2z - e1z * e2y;
    float ny = e1z * e2x - e1x * e2z;
    float nz = e1x * e2y - e1y * e2x;
    float inv = 1.0f / (sqrtf(nx * nx + ny * ny + nz * nz) + 1e-8f);
    nx *= inv; ny *= inv; nz *= inv;

    float4* r = (float4*)(rec + (size_t)i * REC_FLOATS);
    r[0] = make_float4(cx, cy, cz, nx);
    r[1] = make_float4(ny, nz, v0.x, v0.y);
    r[2] = make_float4(v0.z, v1.x, v1.y, v1.z);
    r[3] = make_float4(v2.x, v2.y, v2.z, 0.0f);
}

// ---------------- phase 2: per-pair combine, block partials (no atomics) ----
__global__ __launch_bounds__(256) void pair_kernel(
    const float* __restrict__ rec,        // [B*NF, 16]
    const int2*  __restrict__ cidx,       // [B, NC]
    float*       __restrict__ partials)   // [NPART]
{
    const int b    = blockIdx.x;          // batch -> XCD b%8 (x-major dispatch)
    const int slot = blockIdx.y;
    const int p    = slot * 256 + threadIdx.x;   // pair index within batch
    float pen = 0.0f;

    if (p < NCC) {
        const int2 pr = cidx[(size_t)b * NCC + p];
        if (pr.x >= 0) {
            const int f0 = pr.x;
            const int f1 = pr.y < 0 ? 0 : pr.y;
            const float4* ra = (const float4*)(rec + ((size_t)b * NFF + f0) * REC_FLOATS);
            const float4* rb = (const float4*)(rec + ((size_t)b * NFF + f1) * REC_FLOATS);
            float4 a0 = ra[0], a1 = ra[1], a2 = ra[2], a3 = ra[3];
            float4 b0 = rb[0], b1 = rb[1], b2 = rb[2], b3 = rb[3];

            float3 qa[3] = { make_float3(a1.z, a1.w, a2.x),
                             make_float3(a2.y, a2.z, a2.w),
                             make_float3(a3.x, a3.y, a3.z) };
            float3 qb[3] = { make_float3(b1.z, b1.w, b2.x),
                             make_float3(b2.y, b2.z, b2.w),
                             make_float3(b3.x, b3.y, b3.z) };

            pen = penSide(a0.x, a0.y, a0.z, a0.w, a1.x, a1.y, qb)
                + penSide(b0.x, b0.y, b0.z, b0.w, b1.x, b1.y, qa);
        }
    }

    // wave shuffle reduce
#pragma unroll
    for (int off = 32; off > 0; off >>= 1)
        pen += __shfl_down(pen, off, 64);

    __shared__ float smem[4];
    const int lane = threadIdx.x & 63;
    const int wv   = threadIdx.x >> 6;
    if (lane == 0) smem[wv] = pen;
    __syncthreads();
    if (threadIdx.x == 0)
        partials[(size_t)b * SLOTS + slot] = smem[0] + smem[1] + smem[2] + smem[3];
}

// ---------------- phase 3: fold partials, apply weight/B ----------------
__global__ __launch_bounds__(1024) void reduce_kernel(
    const float* __restrict__ partials,
    const float* __restrict__ weight,
    float*       __restrict__ out)
{
    float s = 0.0f;
    for (int i = threadIdx.x; i < NPART; i += 1024)
        s += partials[i];
#pragma unroll
    for (int off = 32; off > 0; off >>= 1)
        s += __shfl_down(s, off, 64);

    __shared__ float smem[16];
    const int lane = threadIdx.x & 63;
    const int wv   = threadIdx.x >> 6;
    if (lane == 0) smem[wv] = s;
    __syncthreads();
    if (threadIdx.x == 0) {
        float t = 0.0f;
#pragma unroll
        for (int w = 0; w < 16; ++w) t += smem[w];
        out[0] = t * weight[0] * (1.0f / (float)BB);
    }
}

// ---------------- fallback: direct per-pair with atomics (tiny ws) --------
__global__ void init_kernel(float* __restrict__ accum) { accum[0] = 0.0f; }

__device__ __forceinline__ float conePen(float3 a0, float3 a1, float3 a2,
                                         float3 q0, float3 q1, float3 q2) {
    const float third = 1.0f / 3.0f;
    float cx = (a0.x + a1.x + a2.x) * third;
    float cy = (a0.y + a1.y + a2.y) * third;
    float cz = (a0.z + a1.z + a2.z) * third;
    float e1x = a1.x - a0.x, e1y = a1.y - a0.y, e1z = a1.z - a0.z;
    float e2x = a2.x - a0.x, e2y = a2.y - a0.y, e2z = a2.z - a0.z;
    float nx = e1y * e2z - e1z * e2y;
    float ny = e1z * e2x - e1x * e2z;
    float nz = e1x * e2y - e1y * e2x;
    float inv = 1.0f / (sqrtf(nx * nx + ny * ny + nz * nz) + 1e-8f);
    nx *= inv; ny *= inv; nz *= inv;
    float3 q[3] = {q0, q1, q2};
    float pen = 0.0f;
#pragma unroll
    for (int v = 0; v < 3; ++v) {
        float dx = q[v].x - cx, dy = q[v].y - cy, dz = q[v].z - cz;
        float h = dx * nx + dy * ny + dz * nz;
        float r = sqrtf(dx * dx + dy * dy + dz * dz);
        float phi = fmaxf(SIGMA - r, 0.0f);
        pen += (h < 0.0f) ? phi * h * h : 0.0f;
    }
    return pen;
}

__global__ __launch_bounds__(256) void pen_direct(
    const float* __restrict__ vertices, const int* __restrict__ faces,
    const int2* __restrict__ cidx, float* __restrict__ accum)
{
    const int i = blockIdx.x * blockDim.x + threadIdx.x;
    float pen = 0.0f;
    if (i < BB * NCC) {
        const int b = i / NCC;
        const int2 pr = cidx[i];
        if (pr.x >= 0) {
            const int f0 = pr.x;
            const int f1 = pr.y < 0 ? 0 : pr.y;
            const float* vb = vertices + (size_t)b * (NVV * 3);
            float3 a0 = loadv3(vb + (size_t)faces[f0*3+0] * 3);
            float3 a1 = loadv3(vb + (size_t)faces[f0*3+1] * 3);
            float3 a2 = loadv3(vb + (size_t)faces[f0*3+2] * 3);
            float3 b0 = loadv3(vb + (size_t)faces[f1*3+0] * 3);
            float3 b1 = loadv3(vb + (size_t)faces[f1*3+1] * 3);
            float3 b2 = loadv3(vb + (size_t)faces[f1*3+2] * 3);
            pen = conePen(a0,a1,a2,b0,b1,b2) + conePen(b0,b1,b2,a0,a1,a2);
        }
    }
#pragma unroll
    for (int off = 32; off > 0; off >>= 1)
        pen += __shfl_down(pen, off, 64);
    __shared__ float smem[4];
    const int lane = threadIdx.x & 63;
    const int wv   = threadIdx.x >> 6;
    if (lane == 0) smem[wv] = pen;
    __syncthreads();
    if (threadIdx.x == 0)
        atomicAdd(accum, smem[0] + smem[1] + smem[2] + smem[3]);
}

__global__ void fin_kernel(const float* __restrict__ accum,
                           const float* __restrict__ weight,
                           float* __restrict__ out)
{
    out[0] = accum[0] * weight[0] * (1.0f / (float)BB);
}

extern "C" void kernel_launch(void* const* d_in, const int* in_sizes, int n_in,
                              void* d_out, int out_size, void* d_ws, size_t ws_size,
                              hipStream_t stream) {
    const float* vertices = (const float*)d_in[4];
    const float* weight   = (const float*)d_in[5];
    const int*   faces    = (const int*)d_in[6];
    const int2*  cidx     = (const int2*)d_in[7];
    float* out = (float*)d_out;

    if (ws_size >= REC_BYTES + NPART * sizeof(float) + 256) {
        float* rec      = (float*)d_ws;
        float* partials = (float*)((char*)d_ws + REC_BYTES);

        const int totalFaces = BB * NFF;             // 440,832
        face_kernel<<<dim3((totalFaces + 255) / 256), dim3(256), 0, stream>>>(
            vertices, faces, rec);
        pair_kernel<<<dim3(BB, SLOTS), dim3(256), 0, stream>>>(rec, cidx, partials);
        reduce_kernel<<<dim3(1), dim3(1024), 0, stream>>>(partials, weight, out);
    } else {
        float* accum = (float*)d_ws;
        const int totalPairs = BB * NCC;
        init_kernel<<<dim3(1), dim3(1), 0, stream>>>(accum);
        pen_direct<<<dim3((totalPairs + 255) / 256), dim3(256), 0, stream>>>(
            vertices, faces, cidx, accum);
        fin_kernel<<<dim3(1), dim3(1), 0, stream>>>(accum, weight, out);
    }
}

// Round 4
// 131.071 us; speedup vs baseline: 2.1263x; 1.1476x over previous
//
#include <hip/hip_runtime.h>

#define SIGMA 0.5f
#define BB 32
#define NVV 6890
#define NFF 13776
#define MAXC 8
#define NCC (NFF * MAXC)                 // 110208 pairs per batch

// per-(batch,face) record, fp16: c[3], n[3], v0[3], v1[3], v2[3], pad -> 16 halves = 32B
#define REC_HALFS 16
#define REC_BYTES ((size_t)BB * NFF * REC_HALFS * sizeof(_Float16))   // ~14.1 MB

// pair grid: x = batch (32) -> XCD b%8 (x-major dispatch, 32%8==0); y = slot.
// 2 pairs per thread -> 512 pairs per 256-thread block.
#define PAIRS_PER_BLOCK 512
#define SLOTS2 ((NCC + PAIRS_PER_BLOCK - 1) / PAIRS_PER_BLOCK)        // 216
#define NPART (BB * SLOTS2)                                           // 6912

typedef int v4i __attribute__((ext_vector_type(4)));

union RecU {
    uint4    u[2];
    _Float16 h[16];
};

__device__ __forceinline__ float3 loadv3(const float* __restrict__ p) {
    return make_float3(p[0], p[1], p[2]);
}

// ---------------- phase 1: per-(b,f) fp16 face records ----------------
__global__ __launch_bounds__(256) void face_kernel(
    const float* __restrict__ vertices,   // [B, NV, 3]
    const int*   __restrict__ faces,      // [NF, 3]
    uint4*       __restrict__ rec)        // [B*NF][2]
{
    const int i = blockIdx.x * blockDim.x + threadIdx.x;
    if (i >= BB * NFF) return;
    const int b = i / NFF;
    const int f = i - b * NFF;

    const float* vb = vertices + (size_t)b * (NVV * 3);
    const int i0 = faces[f * 3 + 0];
    const int i1 = faces[f * 3 + 1];
    const int i2 = faces[f * 3 + 2];
    float3 v0 = loadv3(vb + (size_t)i0 * 3);
    float3 v1 = loadv3(vb + (size_t)i1 * 3);
    float3 v2 = loadv3(vb + (size_t)i2 * 3);

    const float third = 1.0f / 3.0f;
    float cx = (v0.x + v1.x + v2.x) * third;
    float cy = (v0.y + v1.y + v2.y) * third;
    float cz = (v0.z + v1.z + v2.z) * third;

    float e1x = v1.x - v0.x, e1y = v1.y - v0.y, e1z = v1.z - v0.z;
    float e2x = v2.x - v0.x, e2y = v2.y - v0.y, e2z = v2.z - v0.z;
    float nx = e1y * e2z - e1z * e2y;
    float ny = e1z * e2x - e1x * e2z;
    float nz = e1x * e2y - e1y * e2x;
    float inv = 1.0f / (sqrtf(nx * nx + ny * ny + nz * nz) + 1e-8f);
    nx *= inv; ny *= inv; nz *= inv;

    RecU r;
    r.h[0]  = (_Float16)cx;   r.h[1]  = (_Float16)cy;   r.h[2]  = (_Float16)cz;
    r.h[3]  = (_Float16)nx;   r.h[4]  = (_Float16)ny;   r.h[5]  = (_Float16)nz;
    r.h[6]  = (_Float16)v0.x; r.h[7]  = (_Float16)v0.y; r.h[8]  = (_Float16)v0.z;
    r.h[9]  = (_Float16)v1.x; r.h[10] = (_Float16)v1.y; r.h[11] = (_Float16)v1.z;
    r.h[12] = (_Float16)v2.x; r.h[13] = (_Float16)v2.y; r.h[14] = (_Float16)v2.z;
    r.h[15] = (_Float16)0.0f;

    uint4* dst = rec + (size_t)i * 2;
    dst[0] = r.u[0];
    dst[1] = r.u[1];
}

// one side: query verts (in q[9]) in cone field (c, n)
__device__ __forceinline__ float penSide(float cx, float cy, float cz,
                                         float nx, float ny, float nz,
                                         const float* q) {
    float pen = 0.0f;
#pragma unroll
    for (int v = 0; v < 3; ++v) {
        float dx = q[3 * v + 0] - cx;
        float dy = q[3 * v + 1] - cy;
        float dz = q[3 * v + 2] - cz;
        float h = dx * nx + dy * ny + dz * nz;
        float r = sqrtf(dx * dx + dy * dy + dz * dz);
        float phi = fmaxf(SIGMA - r, 0.0f);
        pen += (h < 0.0f) ? phi * h * h : 0.0f;
    }
    return pen;
}

__device__ __forceinline__ float recPen(const uint4* __restrict__ rec,
                                        int b, int f0, int f1) {
    if (f0 < 0) return 0.0f;                 // padding slot
    const int g1 = f1 < 0 ? 0 : f1;          // reference clamps with max(idx,0)
    const uint4* ra = rec + ((size_t)b * NFF + f0) * 2;
    const uint4* rb = rec + ((size_t)b * NFF + g1) * 2;
    RecU A, B;
    A.u[0] = ra[0]; A.u[1] = ra[1];
    B.u[0] = rb[0]; B.u[1] = rb[1];

    float qa[9], qb[9];
#pragma unroll
    for (int k = 0; k < 9; ++k) { qa[k] = (float)A.h[6 + k]; qb[k] = (float)B.h[6 + k]; }

    float pen = penSide((float)A.h[0], (float)A.h[1], (float)A.h[2],
                        (float)A.h[3], (float)A.h[4], (float)A.h[5], qb);
    pen      += penSide((float)B.h[0], (float)B.h[1], (float)B.h[2],
                        (float)B.h[3], (float)B.h[4], (float)B.h[5], qa);
    return pen;
}

// ---------------- phase 2: per-pair combine, 2 pairs/thread, block partials --
__global__ __launch_bounds__(256) void pair_kernel(
    const uint4* __restrict__ rec,        // [B*NF][2]
    const int*   __restrict__ cidx,       // [B, NC, 2]
    float*       __restrict__ partials)   // [NPART]
{
    const int b    = blockIdx.x;          // batch -> XCD b%8
    const int slot = blockIdx.y;
    const int base = slot * PAIRS_PER_BLOCK + threadIdx.x * 2;   // even, pairs {base, base+1}
    float pen = 0.0f;

    if (base < NCC) {                     // covers base+1 too (NCC even, base even)
        const v4i* c4 = (const v4i*)(cidx + (size_t)b * NCC * 2) + (slot * 256 + threadIdx.x);
        v4i pr = __builtin_nontemporal_load(c4);   // {recv0, intr0, recv1, intr1}
        pen = recPen(rec, b, pr.x, pr.y) + recPen(rec, b, pr.z, pr.w);
    }

    // wave (64-lane) shuffle reduce
#pragma unroll
    for (int off = 32; off > 0; off >>= 1)
        pen += __shfl_down(pen, off, 64);

    __shared__ float smem[4];
    const int lane = threadIdx.x & 63;
    const int wv   = threadIdx.x >> 6;
    if (lane == 0) smem[wv] = pen;
    __syncthreads();
    if (threadIdx.x == 0)
        partials[(size_t)b * SLOTS2 + slot] = smem[0] + smem[1] + smem[2] + smem[3];
}

// ---------------- phase 3: fold partials, apply weight/B ----------------
__global__ __launch_bounds__(1024) void reduce_kernel(
    const float* __restrict__ partials,
    const float* __restrict__ weight,
    float*       __restrict__ out)
{
    float s = 0.0f;
    for (int i = threadIdx.x; i < NPART; i += 1024)
        s += partials[i];
#pragma unroll
    for (int off = 32; off > 0; off >>= 1)
        s += __shfl_down(s, off, 64);

    __shared__ float smem[16];
    const int lane = threadIdx.x & 63;
    const int wv   = threadIdx.x >> 6;
    if (lane == 0) smem[wv] = s;
    __syncthreads();
    if (threadIdx.x == 0) {
        float t = 0.0f;
#pragma unroll
        for (int w = 0; w < 16; ++w) t += smem[w];
        out[0] = t * weight[0] * (1.0f / (float)BB);
    }
}

// ---------------- fallback: direct per-pair with atomics (tiny ws) --------
__global__ void init_kernel(float* __restrict__ accum) { accum[0] = 0.0f; }

__device__ __forceinline__ float conePen(float3 a0, float3 a1, float3 a2,
                                         float3 q0, float3 q1, float3 q2) {
    const float third = 1.0f / 3.0f;
    float cx = (a0.x + a1.x + a2.x) * third;
    float cy = (a0.y + a1.y + a2.y) * third;
    float cz = (a0.z + a1.z + a2.z) * third;
    float e1x = a1.x - a0.x, e1y = a1.y - a0.y, e1z = a1.z - a0.z;
    float e2x = a2.x - a0.x, e2y = a2.y - a0.y, e2z = a2.z - a0.z;
    float nx = e1y * e2z - e1z * e2y;
    float ny = e1z * e2x - e1x * e2z;
    float nz = e1x * e2y - e1y * e2x;
    float inv = 1.0f / (sqrtf(nx * nx + ny * ny + nz * nz) + 1e-8f);
    nx *= inv; ny *= inv; nz *= inv;
    float3 q[3] = {q0, q1, q2};
    float pen = 0.0f;
#pragma unroll
    for (int v = 0; v < 3; ++v) {
        float dx = q[v].x - cx, dy = q[v].y - cy, dz = q[v].z - cz;
        float h = dx * nx + dy * ny + dz * nz;
        float r = sqrtf(dx * dx + dy * dy + dz * dz);
        float phi = fmaxf(SIGMA - r, 0.0f);
        pen += (h < 0.0f) ? phi * h * h : 0.0f;
    }
    return pen;
}

__global__ __launch_bounds__(256) void pen_direct(
    const float* __restrict__ vertices, const int* __restrict__ faces,
    const int2* __restrict__ cidx, float* __restrict__ accum)
{
    const int i = blockIdx.x * blockDim.x + threadIdx.x;
    float pen = 0.0f;
    if (i < BB * NCC) {
        const int b = i / NCC;
        const int2 pr = cidx[i];
        if (pr.x >= 0) {
            const int f0 = pr.x;
            const int f1 = pr.y < 0 ? 0 : pr.y;
            const float* vb = vertices + (size_t)b * (NVV * 3);
            float3 a0 = loadv3(vb + (size_t)faces[f0*3+0] * 3);
            float3 a1 = loadv3(vb + (size_t)faces[f0*3+1] * 3);
            float3 a2 = loadv3(vb + (size_t)faces[f0*3+2] * 3);
            float3 b0 = loadv3(vb + (size_t)faces[f1*3+0] * 3);
            float3 b1 = loadv3(vb + (size_t)faces[f1*3+1] * 3);
            float3 b2 = loadv3(vb + (size_t)faces[f1*3+2] * 3);
            pen = conePen(a0,a1,a2,b0,b1,b2) + conePen(b0,b1,b2,a0,a1,a2);
        }
    }
#pragma unroll
    for (int off = 32; off > 0; off >>= 1)
        pen += __shfl_down(pen, off, 64);
    __shared__ float smem[4];
    const int lane = threadIdx.x & 63;
    const int wv   = threadIdx.x >> 6;
    if (lane == 0) smem[wv] = pen;
    __syncthreads();
    if (threadIdx.x == 0)
        atomicAdd(accum, smem[0] + smem[1] + smem[2] + smem[3]);
}

__global__ void fin_kernel(const float* __restrict__ accum,
                           const float* __restrict__ weight,
                           float* __restrict__ out)
{
    out[0] = accum[0] * weight[0] * (1.0f / (float)BB);
}

extern "C" void kernel_launch(void* const* d_in, const int* in_sizes, int n_in,
                              void* d_out, int out_size, void* d_ws, size_t ws_size,
                              hipStream_t stream) {
    const float* vertices = (const float*)d_in[4];
    const float* weight   = (const float*)d_in[5];
    const int*   faces    = (const int*)d_in[6];
    const int*   cidx     = (const int*)d_in[7];
    float* out = (float*)d_out;

    if (ws_size >= REC_BYTES + NPART * sizeof(float) + 256) {
        uint4* rec      = (uint4*)d_ws;
        float* partials = (float*)((char*)d_ws + REC_BYTES);

        const int totalFaces = BB * NFF;             // 440,832
        face_kernel<<<dim3((totalFaces + 255) / 256), dim3(256), 0, stream>>>(
            vertices, faces, rec);
        pair_kernel<<<dim3(BB, SLOTS2), dim3(256), 0, stream>>>(rec, cidx, partials);
        reduce_kernel<<<dim3(1), dim3(1024), 0, stream>>>(partials, weight, out);
    } else {
        float* accum = (float*)d_ws;
        const int totalPairs = BB * NCC;
        init_kernel<<<dim3(1), dim3(1), 0, stream>>>(accum);
        pen_direct<<<dim3((totalPairs + 255) / 256), dim3(256), 0, stream>>>(
            vertices, faces, (const int2*)cidx, accum);
        fin_kernel<<<dim3(1), dim3(1), 0, stream>>>(accum, weight, out);
    }
}